// Round 5
// baseline (1542.179 us; speedup 1.0000x reference)
//
#include <hip/hip_runtime.h>

#define SS 128
#define BB 32
#define HH 512
#define VV 8000
#define VPAD 8064

typedef __bf16 bf16_t;
typedef __bf16 bf16x8 __attribute__((ext_vector_type(8)));
typedef float  floatx4 __attribute__((ext_vector_type(4)));
typedef unsigned int u32x4 __attribute__((ext_vector_type(4)));

__device__ __forceinline__ float sigmoidf_(float x) { return 1.0f / (1.0f + expf(-x)); }
__device__ __forceinline__ bf16x8 as_bf16x8(u32x4 v) { return __builtin_bit_cast(bf16x8, v); }

// ---------------- workspace layout (bytes) ----------------
// h ring is WRITE-ONCE (one slot per timestep): enables cached consumer reads
// (no address reuse => no stale-line hazard) and removes the ring guard.
#define WS_FLG   0                        // flags[4][64] int = 1024 B
#define WS_HHI   1024                     // h hi [4 gid][128 t][32][512] bf16 = 16777216
#define WS_HLO   (WS_HHI + 16777216)      // h lo, same shape = 16777216
#define WS_XHI   (WS_HLO + 16777216)      // x hi [128][32][512] bf16 = 4194304
#define WS_XLO   (WS_XHI + 4194304)       // x lo = 4194304
#define WS_HOUT  (WS_XLO + 4194304)       // top-layer h [2][128][32][512] bf16 = 8388608
#define WS_WP    (WS_HOUT + 8388608)      // proj weights [2][8064][512] bf16 = 16515072
#define MEMSET_BYTES 1024                 // flags ONLY — h ring must NOT be memset
                                          // (pre-touch would seed stale zero lines)

// LDS: weights 131072 + pbuf 4*32*36*4 = 18432 + bsum 128 -> 149632 (< 160 KiB)
#define SMEM_BYTES 149632

// ---------------- prep kernels ----------------

__global__ __launch_bounds__(256)
void prep_x(const float* __restrict__ x, bf16_t* __restrict__ xh, bf16_t* __restrict__ xl) {
    int i = blockIdx.x * 256 + threadIdx.x;   // 128*32*512 = 2097152 exact
    float v = x[i];
    bf16_t h = (bf16_t)v;
    xh[i] = h;
    xl[i] = (bf16_t)(v - (float)h);
}

__global__ __launch_bounds__(256)
void prep_wp(const float* __restrict__ Wf, const float* __restrict__ Wb, bf16_t* __restrict__ Wp) {
    int i = blockIdx.x * 256 + threadIdx.x;   // 2*8064*512 = 8257536 exact
    int k   = i & 511;
    int rd  = i >> 9;
    int row = rd % 8064;
    int d   = rd / 8064;
    const float* W = d ? Wb : Wf;
    Wp[i] = (row < VV) ? (bf16_t)W[(size_t)row * 512 + k] : (bf16_t)0.0f;
}

// ---------------- persistent LSTM ----------------
// 256 WGs x 512 thr, 1 WG/CU. WG = (d, l, s): 8 h-cols x 4 gates of one (dir,layer).
// Weights (split hi/lo) in LDS, pre-swizzled MFMA fragment order.
// Wave kq (0..7): half = kq>>2 (0: input A, 1: recurrent A), kb = kq&3 (128-k block).
//
// R5 design — per-XCD L2 relay of the h exchange (R4 showed ~2 GB/dispatch of sc1
// h reads through MALL = the residual bottleneck, not the sync protocol):
//  - h ring write-once (128 slots): producers sc1 write-through to MALL + vmcnt
//    drain before flag; consumers use PLAIN CACHED loads. A line can only enter a
//    consumer L2 by a post-flag demand read, and addresses are never rewritten, so
//    cached reads can never be stale. 8-32 WGs/XCD share one L2 copy: MALL read
//    traffic drops ~2 GB -> ~64 MB per dispatch, hit latency ~700 -> ~200 cy.
//  - No ring guard (nothing is overwritten): l=0 never waits on l=1.
//  - XCD-pair placement: bid%8 ~ XCD (dispatch heuristic, perf-only); map bids so
//    group gid occupies XCD pair {2gid, 2gid+1} -> h/flag exchange is 2-XCD-local.
//  - Per-wave polls (R4), s_sleep(2) backoff (R2 lesson), relaxed agent atomics.
//  - Two-phase pbuf, 3 barriers/step. t=0 recurrent input = zero fragments (ring
//    is not pre-zeroed).

__global__ __launch_bounds__(512, 2)
void lstm_persist(const float* __restrict__ Wf_ih, const float* __restrict__ Wf_hh,
                  const float* __restrict__ Wb_ih, const float* __restrict__ Wb_hh,
                  const float* __restrict__ bf_ih, const float* __restrict__ bf_hh,
                  const float* __restrict__ bb_ih, const float* __restrict__ bb_hh,
                  const bf16_t* __restrict__ x_hi, const bf16_t* __restrict__ x_lo,
                  bf16_t* __restrict__ h_hi, bf16_t* __restrict__ h_lo,
                  bf16_t* __restrict__ hout, int* __restrict__ flg)
{
    extern __shared__ char smem[];
    bf16_t* wlds = (bf16_t*)smem;                     // 128 KB weight fragments
    float*  pbuf = (float*)(smem + 131072);           // [4 kb][32 row][36] k-partials
    float*  bsum = (float*)(smem + 131072 + 18432);   // [32] combined bias

    // XCD-pair mapping: gid on XCDs {2gid, 2gid+1} under bid%8 round-robin.
    const int bid  = blockIdx.x;
    const int gid  = (bid & 7) >> 1;
    const int d    = gid >> 1;
    const int l    = gid & 1;
    const int s    = ((bid & 1) << 5) | (bid >> 3);
    const int tid  = threadIdx.x;
    const int lane = tid & 63;
    const int kq   = tid >> 6;
    const int half = kq >> 2;
    const int kb   = kq & 3;
    const int lrow = lane & 15;
    const int quad = lane >> 4;

    const float* Wih = (d ? Wb_ih : Wf_ih) + (size_t)l * (2048 * 512);
    const float* Whh = (d ? Wb_hh : Wf_hh) + (size_t)l * (2048 * 512);

    if (tid < 32) {
        int g = tid >> 3, c = tid & 7;
        int grow = g * 512 + s * 8 + c;
        bsum[tid] = (d ? bb_ih : bf_ih)[l * 2048 + grow] + (d ? bb_hh : bf_hh)[l * 2048 + grow];
    }

    // one-time weight fill: each wave writes exactly the fragments it will read.
    {
        const float* Wsrc = half ? Whh : Wih;
        bf16x8* w8 = (bf16x8*)wlds;
#pragma unroll
        for (int j = 0; j < 4; ++j)
#pragma unroll
            for (int nt = 0; nt < 2; ++nt) {
                int n    = nt * 16 + lrow;
                int grow = (n >> 3) * 512 + s * 8 + (n & 7);
                const float* src = Wsrc + (size_t)grow * 512 + (kb * 128 + j * 32 + quad * 8);
                bf16x8 vh, vl;
#pragma unroll
                for (int e = 0; e < 8; ++e) {
                    float v = src[e];
                    bf16_t hb = (bf16_t)v;
                    vh[e] = hb;
                    vl[e] = (bf16_t)(v - (float)hb);
                }
                int cidx = ((kq * 4 + j) * 2 + nt) * 2;
                w8[(size_t)cidx * 64 + lane]       = vh;
                w8[(size_t)(cidx + 1) * 64 + lane] = vl;
            }
    }
    __syncthreads();

    const bf16x8* wv8 = (const bf16x8*)wlds + (size_t)kq * 1024 + lane;
    const int aoff = lrow * 512 + kb * 128 + quad * 8;
    const bool xwave = (half == 0) && (l == 0);   // wave-uniform: reads x (cached)

    // per-wave flag pointer + threshold offset (wave-uniform)
    const int* wflag = nullptr;   // 64 flags this wave polls
    int  woff = 0;                // threshold = t + woff
    if (half == 1)      { wflag = flg + gid * 64;       woff = 0; }
    else if (l == 1)    { wflag = flg + (gid - 1) * 64; woff = 1; }

    // persistent cell state: epilogue thread (tid<256) owns (b = tid>>3, c = tid&7)
    float creg = 0.0f;

#pragma unroll 1
    for (int t = 0; t < SS; ++t) {
        // A fragments per j: hi-rows0-15 / hi-rows16-31 / lo-rows0-15 / lo-rows16-31
        u32x4 rA0[4], rA1[4], rB0[4], rB1[4];

        // ---- per-wave dependency poll (lane-parallel over 64 flags) ----
        if (wflag) {
            const int thr = t + woff;
            for (;;) {
                int v = __hip_atomic_load(wflag + lane, __ATOMIC_RELAXED, __HIP_MEMORY_SCOPE_AGENT);
                if (__all(v >= thr)) break;
                __builtin_amdgcn_s_sleep(2);
            }
            // compiler fence: forbid hoisting the (plain, cached) h loads above
            // the poll loop. HW issue is in-order; this is a codegen-only fence.
            asm volatile("" ::: "memory");
        }

        // ---- A loads (all plain cached; L2 relays within the XCD pair) ----
        if (xwave) {
            int t_x = d ? (SS - 1 - t) : t;
            const bf16_t* ah = x_hi + (size_t)t_x * 16384 + aoff;
            const bf16_t* al = x_lo + (size_t)t_x * 16384 + aoff;
#pragma unroll
            for (int j = 0; j < 4; ++j) {
                rA0[j] = *(const u32x4*)(ah + j * 32);
                rA1[j] = *(const u32x4*)(ah + 8192 + j * 32);
                rB0[j] = *(const u32x4*)(al + j * 32);
                rB1[j] = *(const u32x4*)(al + 8192 + j * 32);
            }
        } else {
            bool valid;
            size_t po;
            if (half == 0) {   // l==1 input half: layer-0 h at step t (write-once slot)
                valid = true;
                po = ((size_t)(gid - 1) * SS + t) * 16384;
            } else {           // recurrent half: own gid h(t-1); t==0 -> zeros
                valid = (t > 0);
                po = ((size_t)gid * SS + (t > 0 ? t - 1 : 0)) * 16384;
            }
            if (valid) {
                const bf16_t* ah = h_hi + po + aoff;
                const bf16_t* al = h_lo + po + aoff;
#pragma unroll
                for (int j = 0; j < 4; ++j) {
                    rA0[j] = *(const u32x4*)(ah + j * 32);
                    rA1[j] = *(const u32x4*)(ah + 8192 + j * 32);
                    rB0[j] = *(const u32x4*)(al + j * 32);
                    rB1[j] = *(const u32x4*)(al + 8192 + j * 32);
                }
            } else {
#pragma unroll
                for (int j = 0; j < 4; ++j) {
                    rA0[j] = (u32x4){0,0,0,0};
                    rA1[j] = (u32x4){0,0,0,0};
                    rB0[j] = (u32x4){0,0,0,0};
                    rB1[j] = (u32x4){0,0,0,0};
                }
            }
        }

        floatx4 acc00 = {0,0,0,0}, acc01 = {0,0,0,0}, acc10 = {0,0,0,0}, acc11 = {0,0,0,0};
#pragma unroll
        for (int j = 0; j < 4; ++j) {
            bf16x8 b0h = wv8[j * 256];
            bf16x8 b0l = wv8[j * 256 + 64];
            bf16x8 b1h = wv8[j * 256 + 128];
            bf16x8 b1l = wv8[j * 256 + 192];
            bf16x8 ah0 = as_bf16x8(rA0[j]);
            bf16x8 ah1 = as_bf16x8(rA1[j]);
            bf16x8 al0 = as_bf16x8(rB0[j]);
            bf16x8 al1 = as_bf16x8(rB1[j]);
            acc00 = __builtin_amdgcn_mfma_f32_16x16x32_bf16(ah0, b0h, acc00, 0, 0, 0);
            acc00 = __builtin_amdgcn_mfma_f32_16x16x32_bf16(ah0, b0l, acc00, 0, 0, 0);
            acc00 = __builtin_amdgcn_mfma_f32_16x16x32_bf16(al0, b0h, acc00, 0, 0, 0);
            acc01 = __builtin_amdgcn_mfma_f32_16x16x32_bf16(ah0, b1h, acc01, 0, 0, 0);
            acc01 = __builtin_amdgcn_mfma_f32_16x16x32_bf16(ah0, b1l, acc01, 0, 0, 0);
            acc01 = __builtin_amdgcn_mfma_f32_16x16x32_bf16(al0, b1h, acc01, 0, 0, 0);
            acc10 = __builtin_amdgcn_mfma_f32_16x16x32_bf16(ah1, b0h, acc10, 0, 0, 0);
            acc10 = __builtin_amdgcn_mfma_f32_16x16x32_bf16(ah1, b0l, acc10, 0, 0, 0);
            acc10 = __builtin_amdgcn_mfma_f32_16x16x32_bf16(al1, b0h, acc10, 0, 0, 0);
            acc11 = __builtin_amdgcn_mfma_f32_16x16x32_bf16(ah1, b1h, acc11, 0, 0, 0);
            acc11 = __builtin_amdgcn_mfma_f32_16x16x32_bf16(ah1, b1l, acc11, 0, 0, 0);
            acc11 = __builtin_amdgcn_mfma_f32_16x16x32_bf16(al1, b1h, acc11, 0, 0, 0);
        }

        // ---- k-partial reduce, two-phase (no LDS atomics) ----
        if (half == 0) {
#pragma unroll
            for (int rg = 0; rg < 4; ++rg) {
                pbuf[kb * 1152 + (quad * 4 + rg) * 36 + lrow]           = acc00[rg];
                pbuf[kb * 1152 + (quad * 4 + rg) * 36 + 16 + lrow]      = acc01[rg];
                pbuf[kb * 1152 + (16 + quad * 4 + rg) * 36 + lrow]      = acc10[rg];
                pbuf[kb * 1152 + (16 + quad * 4 + rg) * 36 + 16 + lrow] = acc11[rg];
            }
        }
        __syncthreads();   // B_a: write -> add
        if (half == 1) {
#pragma unroll
            for (int rg = 0; rg < 4; ++rg) {
                pbuf[kb * 1152 + (quad * 4 + rg) * 36 + lrow]           += acc00[rg];
                pbuf[kb * 1152 + (quad * 4 + rg) * 36 + 16 + lrow]      += acc01[rg];
                pbuf[kb * 1152 + (16 + quad * 4 + rg) * 36 + lrow]      += acc10[rg];
                pbuf[kb * 1152 + (16 + quad * 4 + rg) * 36 + 16 + lrow] += acc11[rg];
            }
        }
        __syncthreads();   // B_b: add -> epilogue read

        // ---- epilogue: 256 threads, one (batch, col) each; c in register ----
        bf16_t hh_keep = (bf16_t)0.0f;
        if (tid < 256) {
            int b = tid >> 3, c = tid & 7;
            float gi = 0.f, gf_ = 0.f, gg = 0.f, go = 0.f;
#pragma unroll
            for (int kbb = 0; kbb < 4; ++kbb) {
                int base = kbb * 1152 + b * 36 + c;
                gi  += pbuf[base];
                gf_ += pbuf[base + 8];
                gg  += pbuf[base + 16];
                go  += pbuf[base + 24];
            }
            gi += bsum[c]; gf_ += bsum[8 + c]; gg += bsum[16 + c]; go += bsum[24 + c];
            float cn = sigmoidf_(gf_) * creg + sigmoidf_(gi) * tanhf(gg);
            float hn = sigmoidf_(go) * tanhf(cn);
            creg = cn;
            bf16_t hh = (bf16_t)hn;
            bf16_t hl = (bf16_t)(hn - (float)hh);
            hh_keep = hh;
            int col = s * 8 + c;
            size_t ho = ((size_t)gid * SS + t) * 16384 + (size_t)b * HH + col;
            // sc1 write-through to MALL (coherence point for consumer L2 misses);
            // per-thread drain before the barrier+flag.
            unsigned int vh = (unsigned int)__builtin_bit_cast(unsigned short, hh);
            unsigned int vl = (unsigned int)__builtin_bit_cast(unsigned short, hl);
            const bf16_t* ph = h_hi + ho;
            const bf16_t* pl = h_lo + ho;
            asm volatile(
                "global_store_short %0, %2, off sc1\n\t"
                "global_store_short %1, %3, off sc1\n\t"
                "s_waitcnt vmcnt(0)"
                :: "v"(ph), "v"(pl), "v"(vh), "v"(vl)
                : "memory");
        }

        // ---- arrive: barrier (all producer stores drained) then flag store ----
        __syncthreads();   // B_c
        if (tid == 0) {
            __hip_atomic_store(flg + gid * 64 + s, t + 1,
                               __ATOMIC_RELAXED, __HIP_MEMORY_SCOPE_AGENT);
        }
        // hout store after the flag: nothing in-kernel waits on it (proj_gemm input).
        if (l == 1 && tid < 256) {
            int b = tid >> 3, c = tid & 7;
            int col = s * 8 + c;
            int t_x = d ? (SS - 1 - t) : t;
            hout[((size_t)(d * SS + t_x) * BB + b) * HH + col] = hh_keep;
        }
    }
}

// ---------------- projection GEMM ----------------
__global__ __launch_bounds__(256)
void proj_gemm(const bf16_t* __restrict__ hA, const bf16_t* __restrict__ Wp,
               const float* __restrict__ b_fwd, const float* __restrict__ b_bwd,
               float* __restrict__ out)
{
    const int bid = blockIdx.x;
    const int nb  = (bid & 7) + ((bid >> 8) << 3);
    const int mb  = (bid >> 3) & 31;
    if (nb >= 63) return;
    const int d  = blockIdx.z;
    const int n0 = nb * 128;
    const int m0 = mb * 128;
    const bf16_t* A  = hA + (size_t)d * (SS * BB * HH);
    const bf16_t* Bw = Wp + (size_t)d * ((size_t)VPAD * HH);
    const float* bias = d ? b_bwd : b_fwd;
    float* O = out + (size_t)d * ((size_t)SS * BB * VV);

    __shared__ __align__(16) bf16_t lds_a[128 * 40];
    __shared__ __align__(16) bf16_t lds_b[128 * 40];

    const int tid  = threadIdx.x;
    const int lane = tid & 63;
    const int wv   = tid >> 6;
    const int wm   = wv >> 1, wn = wv & 1;
    const int lrow = lane & 15, quad = lane >> 4;

    floatx4 acc[4][4];
#pragma unroll
    for (int i = 0; i < 4; ++i)
#pragma unroll
        for (int j = 0; j < 4; ++j) acc[i][j] = (floatx4){0.f, 0.f, 0.f, 0.f};

    for (int k0 = 0; k0 < HH; k0 += 32) {
        __syncthreads();
#pragma unroll
        for (int q2 = 0; q2 < 2; ++q2) {
            int q = tid * 2 + q2;
            int row = q >> 2, cc = (q & 3) * 8;
            *(bf16x8*)(&lds_a[row * 40 + cc]) = *(const bf16x8*)(A  + (size_t)(m0 + row) * HH + k0 + cc);
            *(bf16x8*)(&lds_b[row * 40 + cc]) = *(const bf16x8*)(Bw + (size_t)(n0 + row) * HH + k0 + cc);
        }
        __syncthreads();
        bf16x8 af[4], bf4[4];
#pragma unroll
        for (int i = 0; i < 4; ++i) {
            af[i]  = *(const bf16x8*)(&lds_a[(wm * 64 + i * 16 + lrow) * 40 + quad * 8]);
            bf4[i] = *(const bf16x8*)(&lds_b[(wn * 64 + i * 16 + lrow) * 40 + quad * 8]);
        }
#pragma unroll
        for (int i = 0; i < 4; ++i)
#pragma unroll
            for (int j = 0; j < 4; ++j)
                acc[i][j] = __builtin_amdgcn_mfma_f32_16x16x32_bf16(af[i], bf4[j], acc[i][j], 0, 0, 0);
    }

#pragma unroll
    for (int j = 0; j < 4; ++j) {
        int n = n0 + wn * 64 + j * 16 + lrow;
        if (n < VV) {
            float bv = bias[n];
#pragma unroll
            for (int i = 0; i < 4; ++i) {
                int mbase = m0 + wm * 64 + i * 16 + quad * 4;
#pragma unroll
                for (int rg = 0; rg < 4; ++rg)
                    O[(size_t)(mbase + rg) * VV + n] = acc[i][j][rg] + bv;
            }
        }
    }
}

// ---------------- launch ----------------

extern "C" void kernel_launch(void* const* d_in, const int* in_sizes, int n_in,
                              void* d_out, int out_size, void* d_ws, size_t ws_size,
                              hipStream_t stream)
{
    const float* x     = (const float*)d_in[0];
    const float* Wf_ih = (const float*)d_in[1];
    const float* Wf_hh = (const float*)d_in[2];
    const float* bf_ih = (const float*)d_in[3];
    const float* bf_hh = (const float*)d_in[4];
    const float* Wb_ih = (const float*)d_in[5];
    const float* Wb_hh = (const float*)d_in[6];
    const float* bb_ih = (const float*)d_in[7];
    const float* bb_hh = (const float*)d_in[8];
    const float* W_fwd = (const float*)d_in[9];
    const float* b_fwd = (const float*)d_in[10];
    const float* W_bwd = (const float*)d_in[11];
    const float* b_bwd = (const float*)d_in[12];
    float* out = (float*)d_out;
    (void)in_sizes; (void)n_in; (void)out_size; (void)ws_size;

    char* ws = (char*)d_ws;
    int*    flg  = (int*)   (ws + WS_FLG);
    bf16_t* h_hi = (bf16_t*)(ws + WS_HHI);
    bf16_t* h_lo = (bf16_t*)(ws + WS_HLO);
    bf16_t* x_hi = (bf16_t*)(ws + WS_XHI);
    bf16_t* x_lo = (bf16_t*)(ws + WS_XLO);
    bf16_t* hout = (bf16_t*)(ws + WS_HOUT);
    bf16_t* Wp   = (bf16_t*)(ws + WS_WP);

    (void)hipFuncSetAttribute(reinterpret_cast<const void*>(lstm_persist),
                              hipFuncAttributeMaxDynamicSharedMemorySize, SMEM_BYTES);

    hipMemsetAsync(ws, 0, MEMSET_BYTES, stream);   // flags only

    prep_x <<<dim3(8192),  256, 0, stream>>>(x, x_hi, x_lo);
    prep_wp<<<dim3(32256), 256, 0, stream>>>(W_fwd, W_bwd, Wp);

    lstm_persist<<<dim3(256), dim3(512), SMEM_BYTES, stream>>>(
        Wf_ih, Wf_hh, Wb_ih, Wb_hh, bf_ih, bf_hh, bb_ih, bb_hh,
        x_hi, x_lo, h_hi, h_lo, hout, flg);

    proj_gemm<<<dim3(2048, 1, 2), 256, 0, stream>>>(hout, Wp, b_fwd, b_bwd, out);
}

// Round 6
// 1398.060 us; speedup vs baseline: 1.1031x; 1.1031x over previous
//
#include <hip/hip_runtime.h>

#define SS 128
#define BB 32
#define HH 512
#define VV 8000
#define VPAD 8064

typedef __bf16 bf16_t;
typedef __bf16 bf16x8 __attribute__((ext_vector_type(8)));
typedef float  floatx4 __attribute__((ext_vector_type(4)));
typedef unsigned int u32x4 __attribute__((ext_vector_type(4)));

__device__ __forceinline__ float sigmoidf_(float x) { return 1.0f / (1.0f + expf(-x)); }
__device__ __forceinline__ bf16x8 as_bf16x8(u32x4 v) { return __builtin_bit_cast(bf16x8, v); }

// ---------------- workspace layout (bytes) ----------------
// Flags: ONE PER 128-B CACHE LINE (R6): 4 groups x 64 WGs x 128 B = 32 KB.
// h ring is WRITE-ONCE (one slot per timestep): cached consumer reads are safe
// (no address reuse => no stale-line hazard) and there is no ring guard.
#define WS_FLG   0                        // flags [4][64] lines = 32768 B
#define WS_HHI   32768                    // h hi [4 gid][128 t][32][512] bf16 = 16777216
#define WS_HLO   (WS_HHI + 16777216)      // h lo = 16777216
#define WS_XHI   (WS_HLO + 16777216)      // x hi [128][32][512] bf16 = 4194304
#define WS_XLO   (WS_XHI + 4194304)       // x lo = 4194304
#define WS_HOUT  (WS_XLO + 4194304)       // top-layer h [2][128][32][512] bf16 = 8388608
#define WS_WP    (WS_HOUT + 8388608)      // proj weights [2][8064][512] bf16 = 16515072
#define MEMSET_BYTES 32768                // flags only — h ring must NOT be pre-touched

// LDS: weights 131072 + pbuf 18432 + bsum 128 + mailbox -> 149760 (< 160 KiB)
#define SMEM_BYTES 149760

// ---------------- prep kernels ----------------

__global__ __launch_bounds__(256)
void prep_x(const float* __restrict__ x, bf16_t* __restrict__ xh, bf16_t* __restrict__ xl) {
    int i = blockIdx.x * 256 + threadIdx.x;   // 128*32*512 = 2097152 exact
    float v = x[i];
    bf16_t h = (bf16_t)v;
    xh[i] = h;
    xl[i] = (bf16_t)(v - (float)h);
}

__global__ __launch_bounds__(256)
void prep_wp(const float* __restrict__ Wf, const float* __restrict__ Wb, bf16_t* __restrict__ Wp) {
    int i = blockIdx.x * 256 + threadIdx.x;   // 2*8064*512 = 8257536 exact
    int k   = i & 511;
    int rd  = i >> 9;
    int row = rd % 8064;
    int d   = rd / 8064;
    const float* W = d ? Wb : Wf;
    Wp[i] = (row < VV) ? (bf16_t)W[(size_t)row * 512 + k] : (bf16_t)0.0f;
}

// ---------------- persistent LSTM ----------------
// 256 WGs x 512 thr, 1 WG/CU. WG = (d, l, s): 8 h-cols x 4 gates of one (dir,layer).
// Weights (split hi/lo) in LDS, pre-swizzled MFMA fragment order.
// Wave kq (0..7): half = kq>>2 (0: input A, 1: recurrent A), kb = kq&3 (128-k block).
//
// R6 — starve the MALL flag lines (R5 proved: not BW-bound, not topology-bound;
// invariant ~9us/step across R1/R4/R5 = poll-storm queueing on 2 flag lines/group;
// R2's no-sleep 2x regression is the same mechanism at higher rate):
//  - ONE global poller wave per WG (wave 7): checks own-group >= t (and prev-group
//    >= t+1 when l=1), then releases sibling waves via an LDS mailbox spin (zero
//    global traffic). B_a already couples all waves per step, so nothing is lost.
//  - One flag per 128-B LINE (32 KB array): a poll wave touches 64 lines once each
//    instead of 64 lanes hammering 2 lines; producer flag stores stop queueing
//    behind other WGs' polls. ~30x less pressure per line.
//  - Keep: s_sleep(2) throttle, relaxed agent atomics, write-once h ring, sc1
//    write-through h stores + vmcnt drain before flag, plain cached h loads,
//    XCD-pair placement, two-phase pbuf, 3 barriers/step.

__global__ __launch_bounds__(512, 2)
void lstm_persist(const float* __restrict__ Wf_ih, const float* __restrict__ Wf_hh,
                  const float* __restrict__ Wb_ih, const float* __restrict__ Wb_hh,
                  const float* __restrict__ bf_ih, const float* __restrict__ bf_hh,
                  const float* __restrict__ bb_ih, const float* __restrict__ bb_hh,
                  const bf16_t* __restrict__ x_hi, const bf16_t* __restrict__ x_lo,
                  bf16_t* __restrict__ h_hi, bf16_t* __restrict__ h_lo,
                  bf16_t* __restrict__ hout, int* __restrict__ flg)
{
    extern __shared__ char smem[];
    bf16_t* wlds  = (bf16_t*)smem;                     // 128 KB weight fragments
    float*  pbuf  = (float*)(smem + 131072);           // [4 kb][32 row][36] k-partials
    float*  bsum  = (float*)(smem + 131072 + 18432);   // [32] combined bias
    int*    ready = (int*)  (smem + 131072 + 18432 + 128);  // step mailbox

    // XCD-pair mapping: gid on XCDs {2gid, 2gid+1} under bid%8 round-robin.
    const int bid  = blockIdx.x;
    const int gid  = (bid & 7) >> 1;
    const int d    = gid >> 1;
    const int l    = gid & 1;
    const int s    = ((bid & 1) << 5) | (bid >> 3);
    const int tid  = threadIdx.x;
    const int lane = tid & 63;
    const int kq   = tid >> 6;
    const int half = kq >> 2;
    const int kb   = kq & 3;
    const int lrow = lane & 15;
    const int quad = lane >> 4;

    const float* Wih = (d ? Wb_ih : Wf_ih) + (size_t)l * (2048 * 512);
    const float* Whh = (d ? Wb_hh : Wf_hh) + (size_t)l * (2048 * 512);

    if (tid < 32) {
        int g = tid >> 3, c = tid & 7;
        int grow = g * 512 + s * 8 + c;
        bsum[tid] = (d ? bb_ih : bf_ih)[l * 2048 + grow] + (d ? bb_hh : bf_hh)[l * 2048 + grow];
    }
    if (tid == 0) *ready = -1;

    // one-time weight fill: each wave writes exactly the fragments it will read.
    {
        const float* Wsrc = half ? Whh : Wih;
        bf16x8* w8 = (bf16x8*)wlds;
#pragma unroll
        for (int j = 0; j < 4; ++j)
#pragma unroll
            for (int nt = 0; nt < 2; ++nt) {
                int n    = nt * 16 + lrow;
                int grow = (n >> 3) * 512 + s * 8 + (n & 7);
                const float* src = Wsrc + (size_t)grow * 512 + (kb * 128 + j * 32 + quad * 8);
                bf16x8 vh, vl;
#pragma unroll
                for (int e = 0; e < 8; ++e) {
                    float v = src[e];
                    bf16_t hb = (bf16_t)v;
                    vh[e] = hb;
                    vl[e] = (bf16_t)(v - (float)hb);
                }
                int cidx = ((kq * 4 + j) * 2 + nt) * 2;
                w8[(size_t)cidx * 64 + lane]       = vh;
                w8[(size_t)(cidx + 1) * 64 + lane] = vl;
            }
    }
    __syncthreads();

    const bf16x8* wv8 = (const bf16x8*)wlds + (size_t)kq * 1024 + lane;
    const int aoff = lrow * 512 + kb * 128 + quad * 8;
    const bool xwave = (half == 0) && (l == 0);   // wave-uniform: reads x, never waits

    // flag line addresses (one int per 128-B line; index stride 32 ints)
    const int* fown  = flg + (size_t)(gid * 64 + lane) * 32;
    const int* fprev = (l == 1) ? (flg + (size_t)((gid - 1) * 64 + lane) * 32) : nullptr;
    const bool spins = (half == 1 && kq != 7) || (l == 1 && half == 0);

    // persistent cell state: epilogue thread (tid<256) owns (b = tid>>3, c = tid&7)
    float creg = 0.0f;

#pragma unroll 1
    for (int t = 0; t < SS; ++t) {
        // A fragments per j: hi-rows0-15 / hi-rows16-31 / lo-rows0-15 / lo-rows16-31
        u32x4 rA0[4], rA1[4], rB0[4], rB1[4];

        // ---- dependency wait: wave 7 polls globals, releases via LDS mailbox ----
        if (kq == 7) {
            for (;;) {
                int a = __hip_atomic_load(fown, __ATOMIC_RELAXED, __HIP_MEMORY_SCOPE_AGENT);
                bool ok = (a >= t);
                if (l == 1) {
                    int b = __hip_atomic_load(fprev, __ATOMIC_RELAXED, __HIP_MEMORY_SCOPE_AGENT);
                    ok = ok && (b >= t + 1);
                }
                if (__all(ok)) break;
                __builtin_amdgcn_s_sleep(2);
            }
            __hip_atomic_store(ready, t, __ATOMIC_RELEASE, __HIP_MEMORY_SCOPE_WORKGROUP);
        } else if (spins) {
            while (__hip_atomic_load(ready, __ATOMIC_ACQUIRE, __HIP_MEMORY_SCOPE_WORKGROUP) < t)
                __builtin_amdgcn_s_sleep(1);
        }
        // codegen fence: forbid hoisting the (plain, cached) loads above the waits.
        asm volatile("" ::: "memory");

        // ---- A loads (plain cached; L2 relays within the XCD pair) ----
        if (xwave) {
            int t_x = d ? (SS - 1 - t) : t;
            const bf16_t* ah = x_hi + (size_t)t_x * 16384 + aoff;
            const bf16_t* al = x_lo + (size_t)t_x * 16384 + aoff;
#pragma unroll
            for (int j = 0; j < 4; ++j) {
                rA0[j] = *(const u32x4*)(ah + j * 32);
                rA1[j] = *(const u32x4*)(ah + 8192 + j * 32);
                rB0[j] = *(const u32x4*)(al + j * 32);
                rB1[j] = *(const u32x4*)(al + 8192 + j * 32);
            }
        } else {
            bool valid;
            size_t po;
            if (half == 0) {   // l==1 input half: layer-0 h at step t (write-once slot)
                valid = true;
                po = ((size_t)(gid - 1) * SS + t) * 16384;
            } else {           // recurrent half: own gid h(t-1); t==0 -> zeros
                valid = (t > 0);
                po = ((size_t)gid * SS + (t > 0 ? t - 1 : 0)) * 16384;
            }
            if (valid) {
                const bf16_t* ah = h_hi + po + aoff;
                const bf16_t* al = h_lo + po + aoff;
#pragma unroll
                for (int j = 0; j < 4; ++j) {
                    rA0[j] = *(const u32x4*)(ah + j * 32);
                    rA1[j] = *(const u32x4*)(ah + 8192 + j * 32);
                    rB0[j] = *(const u32x4*)(al + j * 32);
                    rB1[j] = *(const u32x4*)(al + 8192 + j * 32);
                }
            } else {
#pragma unroll
                for (int j = 0; j < 4; ++j) {
                    rA0[j] = (u32x4){0,0,0,0};
                    rA1[j] = (u32x4){0,0,0,0};
                    rB0[j] = (u32x4){0,0,0,0};
                    rB1[j] = (u32x4){0,0,0,0};
                }
            }
        }

        floatx4 acc00 = {0,0,0,0}, acc01 = {0,0,0,0}, acc10 = {0,0,0,0}, acc11 = {0,0,0,0};
#pragma unroll
        for (int j = 0; j < 4; ++j) {
            bf16x8 b0h = wv8[j * 256];
            bf16x8 b0l = wv8[j * 256 + 64];
            bf16x8 b1h = wv8[j * 256 + 128];
            bf16x8 b1l = wv8[j * 256 + 192];
            bf16x8 ah0 = as_bf16x8(rA0[j]);
            bf16x8 ah1 = as_bf16x8(rA1[j]);
            bf16x8 al0 = as_bf16x8(rB0[j]);
            bf16x8 al1 = as_bf16x8(rB1[j]);
            acc00 = __builtin_amdgcn_mfma_f32_16x16x32_bf16(ah0, b0h, acc00, 0, 0, 0);
            acc00 = __builtin_amdgcn_mfma_f32_16x16x32_bf16(ah0, b0l, acc00, 0, 0, 0);
            acc00 = __builtin_amdgcn_mfma_f32_16x16x32_bf16(al0, b0h, acc00, 0, 0, 0);
            acc01 = __builtin_amdgcn_mfma_f32_16x16x32_bf16(ah0, b1h, acc01, 0, 0, 0);
            acc01 = __builtin_amdgcn_mfma_f32_16x16x32_bf16(ah0, b1l, acc01, 0, 0, 0);
            acc01 = __builtin_amdgcn_mfma_f32_16x16x32_bf16(al0, b1h, acc01, 0, 0, 0);
            acc10 = __builtin_amdgcn_mfma_f32_16x16x32_bf16(ah1, b0h, acc10, 0, 0, 0);
            acc10 = __builtin_amdgcn_mfma_f32_16x16x32_bf16(ah1, b0l, acc10, 0, 0, 0);
            acc10 = __builtin_amdgcn_mfma_f32_16x16x32_bf16(al1, b0h, acc10, 0, 0, 0);
            acc11 = __builtin_amdgcn_mfma_f32_16x16x32_bf16(ah1, b1h, acc11, 0, 0, 0);
            acc11 = __builtin_amdgcn_mfma_f32_16x16x32_bf16(ah1, b1l, acc11, 0, 0, 0);
            acc11 = __builtin_amdgcn_mfma_f32_16x16x32_bf16(al1, b1h, acc11, 0, 0, 0);
        }

        // ---- k-partial reduce, two-phase (no LDS atomics) ----
        if (half == 0) {
#pragma unroll
            for (int rg = 0; rg < 4; ++rg) {
                pbuf[kb * 1152 + (quad * 4 + rg) * 36 + lrow]           = acc00[rg];
                pbuf[kb * 1152 + (quad * 4 + rg) * 36 + 16 + lrow]      = acc01[rg];
                pbuf[kb * 1152 + (16 + quad * 4 + rg) * 36 + lrow]      = acc10[rg];
                pbuf[kb * 1152 + (16 + quad * 4 + rg) * 36 + 16 + lrow] = acc11[rg];
            }
        }
        __syncthreads();   // B_a: write -> add
        if (half == 1) {
#pragma unroll
            for (int rg = 0; rg < 4; ++rg) {
                pbuf[kb * 1152 + (quad * 4 + rg) * 36 + lrow]           += acc00[rg];
                pbuf[kb * 1152 + (quad * 4 + rg) * 36 + 16 + lrow]      += acc01[rg];
                pbuf[kb * 1152 + (16 + quad * 4 + rg) * 36 + lrow]      += acc10[rg];
                pbuf[kb * 1152 + (16 + quad * 4 + rg) * 36 + 16 + lrow] += acc11[rg];
            }
        }
        __syncthreads();   // B_b: add -> epilogue read

        // ---- epilogue: 256 threads, one (batch, col) each; c in register ----
        bf16_t hh_keep = (bf16_t)0.0f;
        if (tid < 256) {
            int b = tid >> 3, c = tid & 7;
            float gi = 0.f, gf_ = 0.f, gg = 0.f, go = 0.f;
#pragma unroll
            for (int kbb = 0; kbb < 4; ++kbb) {
                int base = kbb * 1152 + b * 36 + c;
                gi  += pbuf[base];
                gf_ += pbuf[base + 8];
                gg  += pbuf[base + 16];
                go  += pbuf[base + 24];
            }
            gi += bsum[c]; gf_ += bsum[8 + c]; gg += bsum[16 + c]; go += bsum[24 + c];
            float cn = sigmoidf_(gf_) * creg + sigmoidf_(gi) * tanhf(gg);
            float hn = sigmoidf_(go) * tanhf(cn);
            creg = cn;
            bf16_t hh = (bf16_t)hn;
            bf16_t hl = (bf16_t)(hn - (float)hh);
            hh_keep = hh;
            int col = s * 8 + c;
            size_t ho = ((size_t)gid * SS + t) * 16384 + (size_t)b * HH + col;
            // sc1 write-through to MALL (coherence point for the other XCD of the
            // pair); per-thread drain before the barrier+flag.
            unsigned int vh = (unsigned int)__builtin_bit_cast(unsigned short, hh);
            unsigned int vl = (unsigned int)__builtin_bit_cast(unsigned short, hl);
            const bf16_t* ph = h_hi + ho;
            const bf16_t* pl = h_lo + ho;
            asm volatile(
                "global_store_short %0, %2, off sc1\n\t"
                "global_store_short %1, %3, off sc1\n\t"
                "s_waitcnt vmcnt(0)"
                :: "v"(ph), "v"(pl), "v"(vh), "v"(vl)
                : "memory");
        }

        // ---- arrive: barrier (all producer stores drained) then flag store ----
        __syncthreads();   // B_c
        if (tid == 0) {
            __hip_atomic_store(flg + (size_t)(gid * 64 + s) * 32, t + 1,
                               __ATOMIC_RELAXED, __HIP_MEMORY_SCOPE_AGENT);
        }
        // hout store after the flag: nothing in-kernel waits on it (proj_gemm input).
        if (l == 1 && tid < 256) {
            int b = tid >> 3, c = tid & 7;
            int col = s * 8 + c;
            int t_x = d ? (SS - 1 - t) : t;
            hout[((size_t)(d * SS + t_x) * BB + b) * HH + col] = hh_keep;
        }
    }
}

// ---------------- projection GEMM ----------------
__global__ __launch_bounds__(256)
void proj_gemm(const bf16_t* __restrict__ hA, const bf16_t* __restrict__ Wp,
               const float* __restrict__ b_fwd, const float* __restrict__ b_bwd,
               float* __restrict__ out)
{
    const int bid = blockIdx.x;
    const int nb  = (bid & 7) + ((bid >> 8) << 3);
    const int mb  = (bid >> 3) & 31;
    if (nb >= 63) return;
    const int d  = blockIdx.z;
    const int n0 = nb * 128;
    const int m0 = mb * 128;
    const bf16_t* A  = hA + (size_t)d * (SS * BB * HH);
    const bf16_t* Bw = Wp + (size_t)d * ((size_t)VPAD * HH);
    const float* bias = d ? b_bwd : b_fwd;
    float* O = out + (size_t)d * ((size_t)SS * BB * VV);

    __shared__ __align__(16) bf16_t lds_a[128 * 40];
    __shared__ __align__(16) bf16_t lds_b[128 * 40];

    const int tid  = threadIdx.x;
    const int lane = tid & 63;
    const int wv   = tid >> 6;
    const int wm   = wv >> 1, wn = wv & 1;
    const int lrow = lane & 15, quad = lane >> 4;

    floatx4 acc[4][4];
#pragma unroll
    for (int i = 0; i < 4; ++i)
#pragma unroll
        for (int j = 0; j < 4; ++j) acc[i][j] = (floatx4){0.f, 0.f, 0.f, 0.f};

    for (int k0 = 0; k0 < HH; k0 += 32) {
        __syncthreads();
#pragma unroll
        for (int q2 = 0; q2 < 2; ++q2) {
            int q = tid * 2 + q2;
            int row = q >> 2, cc = (q & 3) * 8;
            *(bf16x8*)(&lds_a[row * 40 + cc]) = *(const bf16x8*)(A  + (size_t)(m0 + row) * HH + k0 + cc);
            *(bf16x8*)(&lds_b[row * 40 + cc]) = *(const bf16x8*)(Bw + (size_t)(n0 + row) * HH + k0 + cc);
        }
        __syncthreads();
        bf16x8 af[4], bf4[4];
#pragma unroll
        for (int i = 0; i < 4; ++i) {
            af[i]  = *(const bf16x8*)(&lds_a[(wm * 64 + i * 16 + lrow) * 40 + quad * 8]);
            bf4[i] = *(const bf16x8*)(&lds_b[(wn * 64 + i * 16 + lrow) * 40 + quad * 8]);
        }
#pragma unroll
        for (int i = 0; i < 4; ++i)
#pragma unroll
            for (int j = 0; j < 4; ++j)
                acc[i][j] = __builtin_amdgcn_mfma_f32_16x16x32_bf16(af[i], bf4[j], acc[i][j], 0, 0, 0);
    }

#pragma unroll
    for (int j = 0; j < 4; ++j) {
        int n = n0 + wn * 64 + j * 16 + lrow;
        if (n < VV) {
            float bv = bias[n];
#pragma unroll
            for (int i = 0; i < 4; ++i) {
                int mbase = m0 + wm * 64 + i * 16 + quad * 4;
#pragma unroll
                for (int rg = 0; rg < 4; ++rg)
                    O[(size_t)(mbase + rg) * VV + n] = acc[i][j][rg] + bv;
            }
        }
    }
}

// ---------------- launch ----------------

extern "C" void kernel_launch(void* const* d_in, const int* in_sizes, int n_in,
                              void* d_out, int out_size, void* d_ws, size_t ws_size,
                              hipStream_t stream)
{
    const float* x     = (const float*)d_in[0];
    const float* Wf_ih = (const float*)d_in[1];
    const float* Wf_hh = (const float*)d_in[2];
    const float* bf_ih = (const float*)d_in[3];
    const float* bf_hh = (const float*)d_in[4];
    const float* Wb_ih = (const float*)d_in[5];
    const float* Wb_hh = (const float*)d_in[6];
    const float* bb_ih = (const float*)d_in[7];
    const float* bb_hh = (const float*)d_in[8];
    const float* W_fwd = (const float*)d_in[9];
    const float* b_fwd = (const float*)d_in[10];
    const float* W_bwd = (const float*)d_in[11];
    const float* b_bwd = (const float*)d_in[12];
    float* out = (float*)d_out;
    (void)in_sizes; (void)n_in; (void)out_size; (void)ws_size;

    char* ws = (char*)d_ws;
    int*    flg  = (int*)   (ws + WS_FLG);
    bf16_t* h_hi = (bf16_t*)(ws + WS_HHI);
    bf16_t* h_lo = (bf16_t*)(ws + WS_HLO);
    bf16_t* x_hi = (bf16_t*)(ws + WS_XHI);
    bf16_t* x_lo = (bf16_t*)(ws + WS_XLO);
    bf16_t* hout = (bf16_t*)(ws + WS_HOUT);
    bf16_t* Wp   = (bf16_t*)(ws + WS_WP);

    (void)hipFuncSetAttribute(reinterpret_cast<const void*>(lstm_persist),
                              hipFuncAttributeMaxDynamicSharedMemorySize, SMEM_BYTES);

    hipMemsetAsync(ws, 0, MEMSET_BYTES, stream);   // flag lines only

    prep_x <<<dim3(8192),  256, 0, stream>>>(x, x_hi, x_lo);
    prep_wp<<<dim3(32256), 256, 0, stream>>>(W_fwd, W_bwd, Wp);

    lstm_persist<<<dim3(256), dim3(512), SMEM_BYTES, stream>>>(
        Wf_ih, Wf_hh, Wb_ih, Wb_hh, bf_ih, bf_hh, bb_ih, bb_hh,
        x_hi, x_lo, h_hi, h_lo, hout, flg);

    proj_gemm<<<dim3(2048, 1, 2), 256, 0, stream>>>(hout, Wp, b_fwd, b_bwd, out);
}

// Round 7
// 1309.698 us; speedup vs baseline: 1.1775x; 1.0675x over previous
//
#include <hip/hip_runtime.h>

#define SS 128
#define BB 32
#define HH 512
#define VV 8000
#define VPAD 8064

typedef __bf16 bf16_t;
typedef __bf16 bf16x8 __attribute__((ext_vector_type(8)));
typedef float  floatx4 __attribute__((ext_vector_type(4)));
typedef unsigned int u32x4 __attribute__((ext_vector_type(4)));

__device__ __forceinline__ float sigmoidf_(float x) { return 1.0f / (1.0f + expf(-x)); }
__device__ __forceinline__ bf16x8 as_bf16x8(u32x4 v) { return __builtin_bit_cast(bf16x8, v); }

// ---------------- workspace layout (bytes) ----------------
// Flags: ONE PER 128-B CACHE LINE: 4 groups x 64 WGs x 128 B = 32 KB.
// h ring is WRITE-ONCE (one slot per timestep): cached consumer reads are safe
// (no address reuse => no stale-line hazard) and there is no ring guard.
#define WS_FLG   0                        // flags [4][64] lines = 32768 B
#define WS_HHI   32768                    // h hi [4 gid][128 t][32][512] bf16 = 16777216
#define WS_HLO   (WS_HHI + 16777216)      // h lo = 16777216
#define WS_XHI   (WS_HLO + 16777216)      // x hi [128][32][512] bf16 = 4194304
#define WS_XLO   (WS_XHI + 4194304)       // x lo = 4194304
#define WS_HOUT  (WS_XLO + 4194304)       // top-layer h [2][128][32][512] bf16 = 8388608
#define WS_WP    (WS_HOUT + 8388608)      // proj weights [2][8064][512] bf16 = 16515072
#define MEMSET_BYTES 32768                // flags only — h ring must NOT be pre-touched

// LDS: weights 131072 + pbuf 18432 + bsum 128 -> 149632 (< 160 KiB)
#define SMEM_BYTES 149632

// ---------------- prep kernels ----------------

__global__ __launch_bounds__(256)
void prep_x(const float* __restrict__ x, bf16_t* __restrict__ xh, bf16_t* __restrict__ xl) {
    int i = blockIdx.x * 256 + threadIdx.x;   // 128*32*512 = 2097152 exact
    float v = x[i];
    bf16_t h = (bf16_t)v;
    xh[i] = h;
    xl[i] = (bf16_t)(v - (float)h);
}

__global__ __launch_bounds__(256)
void prep_wp(const float* __restrict__ Wf, const float* __restrict__ Wb, bf16_t* __restrict__ Wp) {
    int i = blockIdx.x * 256 + threadIdx.x;   // 2*8064*512 = 8257536 exact
    int k   = i & 511;
    int rd  = i >> 9;
    int row = rd % 8064;
    int d   = rd / 8064;
    const float* W = d ? Wb : Wf;
    Wp[i] = (row < VV) ? (bf16_t)W[(size_t)row * 512 + k] : (bf16_t)0.0f;
}

// ---------------- persistent LSTM ----------------
// 256 WGs x 512 thr, 1 WG/CU. WG = (d, l, s): 8 h-cols x 4 gates of one (dir,layer).
// Weights (split hi/lo) in LDS, pre-swizzled MFMA fragment order.
// Wave kq (0..7): half = kq>>2 (0: input A, 1: recurrent A), kb = kq&3 (128-k block).
//
// R7 — radix-16 k-subset waits (R1-R6 established: not BW-bound, not topology-
// bound, not poll-storm-bound alone; the period is ~3 serial MALL RTTs x a
// max-over-64-WGs straggler tail; MFMA busy is a constant 0.65us/step):
//  - Wave kb's 128-k slice of h is produced by exactly 16 WGs (s in [16kb,16kb+16)).
//    Each wave polls ONLY those 16 flag lines (4 lanes/line, coalesced), then
//    immediately loads + MFMAs. E[max16] << E[max64], and early-subset waves'
//    load RTT + MFMA overlap late producers' flag propagation.
//  - No aggregator wave, no LDS mailbox (R6's serial detect->release hop removed).
//  - Keep: line-spread flags, s_sleep(2), relaxed agent atomics, write-once h ring,
//    cached h loads + codegen fence, sc1 h stores + drain before flag, XCD-pair
//    placement, two-phase pbuf, 3 barriers/step.

__global__ __launch_bounds__(512, 2)
void lstm_persist(const float* __restrict__ Wf_ih, const float* __restrict__ Wf_hh,
                  const float* __restrict__ Wb_ih, const float* __restrict__ Wb_hh,
                  const float* __restrict__ bf_ih, const float* __restrict__ bf_hh,
                  const float* __restrict__ bb_ih, const float* __restrict__ bb_hh,
                  const bf16_t* __restrict__ x_hi, const bf16_t* __restrict__ x_lo,
                  bf16_t* __restrict__ h_hi, bf16_t* __restrict__ h_lo,
                  bf16_t* __restrict__ hout, int* __restrict__ flg)
{
    extern __shared__ char smem[];
    bf16_t* wlds  = (bf16_t*)smem;                     // 128 KB weight fragments
    float*  pbuf  = (float*)(smem + 131072);           // [4 kb][32 row][36] k-partials
    float*  bsum  = (float*)(smem + 131072 + 18432);   // [32] combined bias

    // XCD-pair mapping: gid on XCDs {2gid, 2gid+1} under bid%8 round-robin.
    const int bid  = blockIdx.x;
    const int gid  = (bid & 7) >> 1;
    const int d    = gid >> 1;
    const int l    = gid & 1;
    const int s    = ((bid & 1) << 5) | (bid >> 3);
    const int tid  = threadIdx.x;
    const int lane = tid & 63;
    const int kq   = tid >> 6;
    const int half = kq >> 2;
    const int kb   = kq & 3;
    const int lrow = lane & 15;
    const int quad = lane >> 4;

    const float* Wih = (d ? Wb_ih : Wf_ih) + (size_t)l * (2048 * 512);
    const float* Whh = (d ? Wb_hh : Wf_hh) + (size_t)l * (2048 * 512);

    if (tid < 32) {
        int g = tid >> 3, c = tid & 7;
        int grow = g * 512 + s * 8 + c;
        bsum[tid] = (d ? bb_ih : bf_ih)[l * 2048 + grow] + (d ? bb_hh : bf_hh)[l * 2048 + grow];
    }

    // one-time weight fill: each wave writes exactly the fragments it will read.
    {
        const float* Wsrc = half ? Whh : Wih;
        bf16x8* w8 = (bf16x8*)wlds;
#pragma unroll
        for (int j = 0; j < 4; ++j)
#pragma unroll
            for (int nt = 0; nt < 2; ++nt) {
                int n    = nt * 16 + lrow;
                int grow = (n >> 3) * 512 + s * 8 + (n & 7);
                const float* src = Wsrc + (size_t)grow * 512 + (kb * 128 + j * 32 + quad * 8);
                bf16x8 vh, vl;
#pragma unroll
                for (int e = 0; e < 8; ++e) {
                    float v = src[e];
                    bf16_t hb = (bf16_t)v;
                    vh[e] = hb;
                    vl[e] = (bf16_t)(v - (float)hb);
                }
                int cidx = ((kq * 4 + j) * 2 + nt) * 2;
                w8[(size_t)cidx * 64 + lane]       = vh;
                w8[(size_t)(cidx + 1) * 64 + lane] = vl;
            }
    }
    __syncthreads();

    const bf16x8* wv8 = (const bf16x8*)wlds + (size_t)kq * 1024 + lane;
    const int aoff = lrow * 512 + kb * 128 + quad * 8;
    const bool xwave = (half == 0) && (l == 0);   // wave-uniform: reads x, never waits

    // per-wave dependency: the 16 producers of this wave's 128-k slice.
    // Lane layout: 4 lanes share each producer's flag line (same addr -> 1 req/line).
    const int  pidx  = kb * 16 + (lane & 15);
    const int* wflag = nullptr;
    int woff = 0;
    if (half == 1)   { wflag = flg + (size_t)(gid * 64 + pidx) * 32;       woff = 0; }
    else if (l == 1) { wflag = flg + (size_t)((gid - 1) * 64 + pidx) * 32; woff = 1; }

    // persistent cell state: epilogue thread (tid<256) owns (b = tid>>3, c = tid&7)
    float creg = 0.0f;

#pragma unroll 1
    for (int t = 0; t < SS; ++t) {
        // A fragments per j: hi-rows0-15 / hi-rows16-31 / lo-rows0-15 / lo-rows16-31
        u32x4 rA0[4], rA1[4], rB0[4], rB1[4];

        // ---- per-wave k-subset poll (16 producers, lane-parallel) ----
        if (wflag) {
            const int thr = t + woff;
            for (;;) {
                int v = __hip_atomic_load(wflag, __ATOMIC_RELAXED, __HIP_MEMORY_SCOPE_AGENT);
                if (__all(v >= thr)) break;
                __builtin_amdgcn_s_sleep(2);
            }
            // codegen fence: forbid hoisting the (plain, cached) loads above the poll.
            asm volatile("" ::: "memory");
        }

        // ---- A loads (plain cached; L2 relays within the XCD pair) ----
        if (xwave) {
            int t_x = d ? (SS - 1 - t) : t;
            const bf16_t* ah = x_hi + (size_t)t_x * 16384 + aoff;
            const bf16_t* al = x_lo + (size_t)t_x * 16384 + aoff;
#pragma unroll
            for (int j = 0; j < 4; ++j) {
                rA0[j] = *(const u32x4*)(ah + j * 32);
                rA1[j] = *(const u32x4*)(ah + 8192 + j * 32);
                rB0[j] = *(const u32x4*)(al + j * 32);
                rB1[j] = *(const u32x4*)(al + 8192 + j * 32);
            }
        } else {
            bool valid;
            size_t po;
            if (half == 0) {   // l==1 input half: layer-0 h at step t (write-once slot)
                valid = true;
                po = ((size_t)(gid - 1) * SS + t) * 16384;
            } else {           // recurrent half: own gid h(t-1); t==0 -> zeros
                valid = (t > 0);
                po = ((size_t)gid * SS + (t > 0 ? t - 1 : 0)) * 16384;
            }
            if (valid) {
                const bf16_t* ah = h_hi + po + aoff;
                const bf16_t* al = h_lo + po + aoff;
#pragma unroll
                for (int j = 0; j < 4; ++j) {
                    rA0[j] = *(const u32x4*)(ah + j * 32);
                    rA1[j] = *(const u32x4*)(ah + 8192 + j * 32);
                    rB0[j] = *(const u32x4*)(al + j * 32);
                    rB1[j] = *(const u32x4*)(al + 8192 + j * 32);
                }
            } else {
#pragma unroll
                for (int j = 0; j < 4; ++j) {
                    rA0[j] = (u32x4){0,0,0,0};
                    rA1[j] = (u32x4){0,0,0,0};
                    rB0[j] = (u32x4){0,0,0,0};
                    rB1[j] = (u32x4){0,0,0,0};
                }
            }
        }

        floatx4 acc00 = {0,0,0,0}, acc01 = {0,0,0,0}, acc10 = {0,0,0,0}, acc11 = {0,0,0,0};
#pragma unroll
        for (int j = 0; j < 4; ++j) {
            bf16x8 b0h = wv8[j * 256];
            bf16x8 b0l = wv8[j * 256 + 64];
            bf16x8 b1h = wv8[j * 256 + 128];
            bf16x8 b1l = wv8[j * 256 + 192];
            bf16x8 ah0 = as_bf16x8(rA0[j]);
            bf16x8 ah1 = as_bf16x8(rA1[j]);
            bf16x8 al0 = as_bf16x8(rB0[j]);
            bf16x8 al1 = as_bf16x8(rB1[j]);
            acc00 = __builtin_amdgcn_mfma_f32_16x16x32_bf16(ah0, b0h, acc00, 0, 0, 0);
            acc00 = __builtin_amdgcn_mfma_f32_16x16x32_bf16(ah0, b0l, acc00, 0, 0, 0);
            acc00 = __builtin_amdgcn_mfma_f32_16x16x32_bf16(al0, b0h, acc00, 0, 0, 0);
            acc01 = __builtin_amdgcn_mfma_f32_16x16x32_bf16(ah0, b1h, acc01, 0, 0, 0);
            acc01 = __builtin_amdgcn_mfma_f32_16x16x32_bf16(ah0, b1l, acc01, 0, 0, 0);
            acc01 = __builtin_amdgcn_mfma_f32_16x16x32_bf16(al0, b1h, acc01, 0, 0, 0);
            acc10 = __builtin_amdgcn_mfma_f32_16x16x32_bf16(ah1, b0h, acc10, 0, 0, 0);
            acc10 = __builtin_amdgcn_mfma_f32_16x16x32_bf16(ah1, b0l, acc10, 0, 0, 0);
            acc10 = __builtin_amdgcn_mfma_f32_16x16x32_bf16(al1, b0h, acc10, 0, 0, 0);
            acc11 = __builtin_amdgcn_mfma_f32_16x16x32_bf16(ah1, b1h, acc11, 0, 0, 0);
            acc11 = __builtin_amdgcn_mfma_f32_16x16x32_bf16(ah1, b1l, acc11, 0, 0, 0);
            acc11 = __builtin_amdgcn_mfma_f32_16x16x32_bf16(al1, b1h, acc11, 0, 0, 0);
        }

        // ---- k-partial reduce, two-phase (no LDS atomics) ----
        if (half == 0) {
#pragma unroll
            for (int rg = 0; rg < 4; ++rg) {
                pbuf[kb * 1152 + (quad * 4 + rg) * 36 + lrow]           = acc00[rg];
                pbuf[kb * 1152 + (quad * 4 + rg) * 36 + 16 + lrow]      = acc01[rg];
                pbuf[kb * 1152 + (16 + quad * 4 + rg) * 36 + lrow]      = acc10[rg];
                pbuf[kb * 1152 + (16 + quad * 4 + rg) * 36 + 16 + lrow] = acc11[rg];
            }
        }
        __syncthreads();   // B_a: write -> add
        if (half == 1) {
#pragma unroll
            for (int rg = 0; rg < 4; ++rg) {
                pbuf[kb * 1152 + (quad * 4 + rg) * 36 + lrow]           += acc00[rg];
                pbuf[kb * 1152 + (quad * 4 + rg) * 36 + 16 + lrow]      += acc01[rg];
                pbuf[kb * 1152 + (16 + quad * 4 + rg) * 36 + lrow]      += acc10[rg];
                pbuf[kb * 1152 + (16 + quad * 4 + rg) * 36 + 16 + lrow] += acc11[rg];
            }
        }
        __syncthreads();   // B_b: add -> epilogue read

        // ---- epilogue: 256 threads, one (batch, col) each; c in register ----
        bf16_t hh_keep = (bf16_t)0.0f;
        if (tid < 256) {
            int b = tid >> 3, c = tid & 7;
            float gi = 0.f, gf_ = 0.f, gg = 0.f, go = 0.f;
#pragma unroll
            for (int kbb = 0; kbb < 4; ++kbb) {
                int base = kbb * 1152 + b * 36 + c;
                gi  += pbuf[base];
                gf_ += pbuf[base + 8];
                gg  += pbuf[base + 16];
                go  += pbuf[base + 24];
            }
            gi += bsum[c]; gf_ += bsum[8 + c]; gg += bsum[16 + c]; go += bsum[24 + c];
            float cn = sigmoidf_(gf_) * creg + sigmoidf_(gi) * tanhf(gg);
            float hn = sigmoidf_(go) * tanhf(cn);
            creg = cn;
            bf16_t hh = (bf16_t)hn;
            bf16_t hl = (bf16_t)(hn - (float)hh);
            hh_keep = hh;
            int col = s * 8 + c;
            size_t ho = ((size_t)gid * SS + t) * 16384 + (size_t)b * HH + col;
            // sc1 write-through to MALL (coherence point for the other XCD of the
            // pair); per-thread drain before the barrier+flag.
            unsigned int vh = (unsigned int)__builtin_bit_cast(unsigned short, hh);
            unsigned int vl = (unsigned int)__builtin_bit_cast(unsigned short, hl);
            const bf16_t* ph = h_hi + ho;
            const bf16_t* pl = h_lo + ho;
            asm volatile(
                "global_store_short %0, %2, off sc1\n\t"
                "global_store_short %1, %3, off sc1\n\t"
                "s_waitcnt vmcnt(0)"
                :: "v"(ph), "v"(pl), "v"(vh), "v"(vl)
                : "memory");
        }

        // ---- arrive: barrier (all producer stores drained) then flag store ----
        __syncthreads();   // B_c
        if (tid == 0) {
            __hip_atomic_store(flg + (size_t)(gid * 64 + s) * 32, t + 1,
                               __ATOMIC_RELAXED, __HIP_MEMORY_SCOPE_AGENT);
        }
        // hout store after the flag: nothing in-kernel waits on it (proj_gemm input).
        if (l == 1 && tid < 256) {
            int b = tid >> 3, c = tid & 7;
            int col = s * 8 + c;
            int t_x = d ? (SS - 1 - t) : t;
            hout[((size_t)(d * SS + t_x) * BB + b) * HH + col] = hh_keep;
        }
    }
}

// ---------------- projection GEMM ----------------
__global__ __launch_bounds__(256)
void proj_gemm(const bf16_t* __restrict__ hA, const bf16_t* __restrict__ Wp,
               const float* __restrict__ b_fwd, const float* __restrict__ b_bwd,
               float* __restrict__ out)
{
    const int bid = blockIdx.x;
    const int nb  = (bid & 7) + ((bid >> 8) << 3);
    const int mb  = (bid >> 3) & 31;
    if (nb >= 63) return;
    const int d  = blockIdx.z;
    const int n0 = nb * 128;
    const int m0 = mb * 128;
    const bf16_t* A  = hA + (size_t)d * (SS * BB * HH);
    const bf16_t* Bw = Wp + (size_t)d * ((size_t)VPAD * HH);
    const float* bias = d ? b_bwd : b_fwd;
    float* O = out + (size_t)d * ((size_t)SS * BB * VV);

    __shared__ __align__(16) bf16_t lds_a[128 * 40];
    __shared__ __align__(16) bf16_t lds_b[128 * 40];

    const int tid  = threadIdx.x;
    const int lane = tid & 63;
    const int wv   = tid >> 6;
    const int wm   = wv >> 1, wn = wv & 1;
    const int lrow = lane & 15, quad = lane >> 4;

    floatx4 acc[4][4];
#pragma unroll
    for (int i = 0; i < 4; ++i)
#pragma unroll
        for (int j = 0; j < 4; ++j) acc[i][j] = (floatx4){0.f, 0.f, 0.f, 0.f};

    for (int k0 = 0; k0 < HH; k0 += 32) {
        __syncthreads();
#pragma unroll
        for (int q2 = 0; q2 < 2; ++q2) {
            int q = tid * 2 + q2;
            int row = q >> 2, cc = (q & 3) * 8;
            *(bf16x8*)(&lds_a[row * 40 + cc]) = *(const bf16x8*)(A  + (size_t)(m0 + row) * HH + k0 + cc);
            *(bf16x8*)(&lds_b[row * 40 + cc]) = *(const bf16x8*)(Bw + (size_t)(n0 + row) * HH + k0 + cc);
        }
        __syncthreads();
        bf16x8 af[4], bf4[4];
#pragma unroll
        for (int i = 0; i < 4; ++i) {
            af[i]  = *(const bf16x8*)(&lds_a[(wm * 64 + i * 16 + lrow) * 40 + quad * 8]);
            bf4[i] = *(const bf16x8*)(&lds_b[(wn * 64 + i * 16 + lrow) * 40 + quad * 8]);
        }
#pragma unroll
        for (int i = 0; i < 4; ++i)
#pragma unroll
            for (int j = 0; j < 4; ++j)
                acc[i][j] = __builtin_amdgcn_mfma_f32_16x16x32_bf16(af[i], bf4[j], acc[i][j], 0, 0, 0);
    }

#pragma unroll
    for (int j = 0; j < 4; ++j) {
        int n = n0 + wn * 64 + j * 16 + lrow;
        if (n < VV) {
            float bv = bias[n];
#pragma unroll
            for (int i = 0; i < 4; ++i) {
                int mbase = m0 + wm * 64 + i * 16 + quad * 4;
#pragma unroll
                for (int rg = 0; rg < 4; ++rg)
                    O[(size_t)(mbase + rg) * VV + n] = acc[i][j][rg] + bv;
            }
        }
    }
}

// ---------------- launch ----------------

extern "C" void kernel_launch(void* const* d_in, const int* in_sizes, int n_in,
                              void* d_out, int out_size, void* d_ws, size_t ws_size,
                              hipStream_t stream)
{
    const float* x     = (const float*)d_in[0];
    const float* Wf_ih = (const float*)d_in[1];
    const float* Wf_hh = (const float*)d_in[2];
    const float* bf_ih = (const float*)d_in[3];
    const float* bf_hh = (const float*)d_in[4];
    const float* Wb_ih = (const float*)d_in[5];
    const float* Wb_hh = (const float*)d_in[6];
    const float* bb_ih = (const float*)d_in[7];
    const float* bb_hh = (const float*)d_in[8];
    const float* W_fwd = (const float*)d_in[9];
    const float* b_fwd = (const float*)d_in[10];
    const float* W_bwd = (const float*)d_in[11];
    const float* b_bwd = (const float*)d_in[12];
    float* out = (float*)d_out;
    (void)in_sizes; (void)n_in; (void)out_size; (void)ws_size;

    char* ws = (char*)d_ws;
    int*    flg  = (int*)   (ws + WS_FLG);
    bf16_t* h_hi = (bf16_t*)(ws + WS_HHI);
    bf16_t* h_lo = (bf16_t*)(ws + WS_HLO);
    bf16_t* x_hi = (bf16_t*)(ws + WS_XHI);
    bf16_t* x_lo = (bf16_t*)(ws + WS_XLO);
    bf16_t* hout = (bf16_t*)(ws + WS_HOUT);
    bf16_t* Wp   = (bf16_t*)(ws + WS_WP);

    (void)hipFuncSetAttribute(reinterpret_cast<const void*>(lstm_persist),
                              hipFuncAttributeMaxDynamicSharedMemorySize, SMEM_BYTES);

    hipMemsetAsync(ws, 0, MEMSET_BYTES, stream);   // flag lines only

    prep_x <<<dim3(8192),  256, 0, stream>>>(x, x_hi, x_lo);
    prep_wp<<<dim3(32256), 256, 0, stream>>>(W_fwd, W_bwd, Wp);

    lstm_persist<<<dim3(256), dim3(512), SMEM_BYTES, stream>>>(
        Wf_ih, Wf_hh, Wb_ih, Wb_hh, bf_ih, bf_hh, bb_ih, bb_hh,
        x_hi, x_lo, h_hi, h_lo, hout, flg);

    proj_gemm<<<dim3(2048, 1, 2), 256, 0, stream>>>(hout, Wp, b_fwd, b_bwd, out);
}